// Round 6
// baseline (5953.035 us; speedup 1.0000x reference)
//
#include <hip/hip_runtime.h>
#include <hip/hip_fp16.h>
#include <math.h>

constexpr int B_ = 64;
constexpr int N_ = 4096;
constexpr int D_ = 256;
constexpr int NCH = 64;            // chunks (blocks) per batch row
constexpr int NPB = N_ / NCH;      // 64 rows per block
constexpr int NPW = NPB / 4;       // 16 rows per wave
constexpr int NSTEP = NPW / 4;     // 4 steps; each step = 4 rows (one per 16-lane group)

// Non-temporal float4 load (read-once fp32 means must not thrash L3).
__device__ inline float4 nt_load4(const float* p) {
    typedef float f32x4 __attribute__((ext_vector_type(4)));
    f32x4 r = __builtin_nontemporal_load((const f32x4*)p);
    return make_float4(r.x, r.y, r.z, r.w);
}

// ---------------------------------------------------------------------------
// flag: is precision == I?  Also zeroes the per-iteration arrival counters.
// ---------------------------------------------------------------------------
__global__ __launch_bounds__(256) void flag_kernel(const float* __restrict__ P,
                                                   int* __restrict__ flag,
                                                   int* __restrict__ counters,
                                                   int ncounters) {
    __shared__ int sh[256];
    const int tid = threadIdx.x;
    for (int i = tid; i < ncounters; i += 256) counters[i] = 0;
    int bad = 0;
    for (int i = tid; i < D_ * D_; i += 256) {
        const int r = i >> 8, c = i & 255;
        const float expect = (r == c) ? 1.0f : 0.0f;
        bad |= (P[i] != expect) ? 1 : 0;
    }
    sh[tid] = bad;
    __syncthreads();
    for (int s = 128; s > 0; s >>= 1) {
        if (tid < s) sh[tid] |= sh[tid + s];
        __syncthreads();
    }
    if (tid == 0) *flag = sh[0];
}

// v = (P + P^T) z  — fast path v = 2z when P == I.
__global__ __launch_bounds__(256) void vcalc_kernel(const float* __restrict__ P,
                                                    const float* __restrict__ z,
                                                    const int* __restrict__ flag,
                                                    float* __restrict__ v) {
    __shared__ float zsh[D_];
    const int b = blockIdx.x, d = threadIdx.x;
    const float zd = z[b * D_ + d];
    if (*flag == 0) {
        v[b * D_ + d] = 2.0f * zd;
        return;
    }
    zsh[d] = zd;
    __syncthreads();
    float acc = 0.f;
    for (int e = 0; e < D_; e++)
        acc += (P[d * D_ + e] + P[e * D_ + d]) * zsh[e];
    v[b * D_ + d] = acc;
}

// ---------------------------------------------------------------------------
// Per-row score + online-softmax update. Expects in scope:
// m[4] (fragment, d = q*8+128*(j>>1)+4*(j&1)+c), vr[4], runM, runS, tacc[4],
// flg, srows, wave, g, q, P.
// ---------------------------------------------------------------------------
#define SCORE_AND_UPDATE()                                                     \
    {                                                                          \
        float p_ = 0.f;                                                        \
        _Pragma("unroll")                                                      \
        for (int j = 0; j < 4; j++) {                                          \
            p_ += m[j].x * (vr[j].x - m[j].x);                                 \
            p_ += m[j].y * (vr[j].y - m[j].y);                                 \
            p_ += m[j].z * (vr[j].z - m[j].z);                                 \
            p_ += m[j].w * (vr[j].w - m[j].w);                                 \
        }                                                                      \
        p_ += __shfl_xor(p_, 1, 64);                                           \
        p_ += __shfl_xor(p_, 2, 64);                                           \
        p_ += __shfl_xor(p_, 4, 64);                                           \
        p_ += __shfl_xor(p_, 8, 64);                                           \
        float s_ = 0.5f * p_;                                                  \
        if (flg) { /* general P: s += 0.5*(||m||^2 - m^T P m) */               \
            __syncthreads();                                                   \
            _Pragma("unroll")                                                  \
            for (int jj = 0; jj < 2; jj++)                                     \
                _Pragma("unroll")                                              \
                for (int h = 0; h < 2; h++)                                    \
                    ((float4*)&srows[wave][g][0])[q * 2 + 32 * jj + h] =       \
                        m[jj * 2 + h];                                         \
            __syncthreads();                                                   \
            float dl = 0.f;                                                    \
            for (int k = 0; k < 16; k++) {                                     \
                const int d_ = q * 16 + k;                                     \
                const float md = srows[wave][g][d_];                           \
                float pm = 0.f;                                                \
                for (int e = 0; e < D_; e++)                                   \
                    pm += P[d_ * D_ + e] * srows[wave][g][e];                  \
                dl += md * (md - pm);                                          \
            }                                                                  \
            dl += __shfl_xor(dl, 1, 64);                                       \
            dl += __shfl_xor(dl, 2, 64);                                       \
            dl += __shfl_xor(dl, 4, 64);                                       \
            dl += __shfl_xor(dl, 8, 64);                                       \
            s_ += 0.5f * dl;                                                   \
        }                                                                      \
        const float newM_ = fmaxf(runM, s_);                                   \
        const float sc_ = __expf(runM - newM_);                                \
        const float e_  = __expf(s_ - newM_);                                  \
        runS = fmaf(runS, sc_, e_);                                            \
        _Pragma("unroll")                                                      \
        for (int j = 0; j < 4; j++) {                                          \
            tacc[j].x = fmaf(tacc[j].x, sc_, e_ * m[j].x);                     \
            tacc[j].y = fmaf(tacc[j].y, sc_, e_ * m[j].y);                     \
            tacc[j].z = fmaf(tacc[j].z, sc_, e_ * m[j].z);                     \
            tacc[j].w = fmaf(tacc[j].w, sc_, e_ * m[j].w);                     \
        }                                                                      \
        runM = newM_;                                                          \
    }

// ---------------------------------------------------------------------------
// Fused kernel: scores + online softmax + partials, then last-block-per-b
// combine (device-scope atomic arrival counter) -> z, v for next iteration.
// MODE 0: fp32 read.  MODE 1: fp32 NT read + fp16 copy write.  MODE 2: fp16 read.
// ---------------------------------------------------------------------------
template <int MODE>
__global__ __launch_bounds__(256) void fused_kernel(
        const float* __restrict__ means, const __half* __restrict__ mhr,
        __half* __restrict__ mhw, const float* __restrict__ v,
        const float* __restrict__ P, const int* __restrict__ flag,
        float* __restrict__ Tbuf, float2* __restrict__ stats,
        int* __restrict__ counter,        // B_ ints for THIS iteration
        float* __restrict__ vout, float* __restrict__ out) {
    const int b = blockIdx.y, chunk = blockIdx.x;
    const int tid = threadIdx.x, wave = tid >> 6, lane = tid & 63;
    const int q = lane & 15, g = lane >> 4;
    __shared__ __align__(16) float vsh[D_];
    __shared__ __align__(16) float shbuf[4][D_];
    __shared__ __align__(16) float srows[4][4][D_];   // slow path only
    __shared__ __align__(16) float zsh[D_];
    __shared__ float wM[4], wS[4];
    __shared__ float Msh[NCH], Ssh[NCH];
    __shared__ int lastFlag;
    vsh[tid] = v[b * D_ + tid];
    __syncthreads();
    float4 vr[4];   // vr[jj*2+h] covers d = q*8 + 128*jj + 4*h
    #pragma unroll
    for (int jj = 0; jj < 2; jj++)
        #pragma unroll
        for (int h = 0; h < 2; h++)
            vr[jj * 2 + h] = ((const float4*)vsh)[q * 2 + 32 * jj + h];
    const int flg = *flag;

    float runM = -INFINITY, runS = 0.f;
    float4 tacc[4];
    #pragma unroll
    for (int j = 0; j < 4; j++) tacc[j] = make_float4(0.f, 0.f, 0.f, 0.f);

    const size_t rowbase = (size_t)b * N_ + (size_t)chunk * NPB + (size_t)wave * NPW;

    if (MODE == 2) {
        // hoist ALL 8 float4 loads (4 steps x 2) for max memory-level parallelism
        float4 raw[NSTEP][2];
        #pragma unroll
        for (int step = 0; step < NSTEP; step++) {
            const __half* rp = mhr + (rowbase + step * 4 + g) * D_;
            #pragma unroll
            for (int jj = 0; jj < 2; jj++)
                raw[step][jj] = ((const float4*)rp)[q + 16 * jj];
        }
        #pragma unroll
        for (int step = 0; step < NSTEP; step++) {
            float4 m[4];
            #pragma unroll
            for (int jj = 0; jj < 2; jj++) {
                const __half2* hp2 = (const __half2*)&raw[step][jj];
                const float2 f0 = __half22float2(hp2[0]);
                const float2 f1 = __half22float2(hp2[1]);
                const float2 f2 = __half22float2(hp2[2]);
                const float2 f3 = __half22float2(hp2[3]);
                m[jj * 2 + 0] = make_float4(f0.x, f0.y, f1.x, f1.y);
                m[jj * 2 + 1] = make_float4(f2.x, f2.y, f3.x, f3.y);
            }
            SCORE_AND_UPDATE()
        }
    } else {
        for (int step = 0; step < NSTEP; step++) {
            const int r = step * 4 + g;
            const float* rp = means + (rowbase + r) * D_;
            float4 m[4];
            #pragma unroll
            for (int jj = 0; jj < 2; jj++)
                #pragma unroll
                for (int h = 0; h < 2; h++)
                    m[jj * 2 + h] = nt_load4(rp + (q * 2 + 32 * jj + h) * 4);
            if (MODE == 1) {
                __half* hp = mhw + (rowbase + r) * D_;
                #pragma unroll
                for (int jj = 0; jj < 2; jj++) {
                    union { uint4 u4; __half2 h2[4]; } pk;
                    pk.h2[0] = __floats2half2_rn(m[jj*2].x,   m[jj*2].y);
                    pk.h2[1] = __floats2half2_rn(m[jj*2].z,   m[jj*2].w);
                    pk.h2[2] = __floats2half2_rn(m[jj*2+1].x, m[jj*2+1].y);
                    pk.h2[3] = __floats2half2_rn(m[jj*2+1].z, m[jj*2+1].w);
                    *(uint4*)(hp + q * 8 + 128 * jj) = pk.u4;
                }
            }
            SCORE_AND_UPDATE()
        }
    }

    // ---- epilogue: combine 4 lane-groups (xor 16/32), then 4 waves ----
    float Mw = runM;
    Mw = fmaxf(Mw, __shfl_xor(Mw, 16, 64));
    Mw = fmaxf(Mw, __shfl_xor(Mw, 32, 64));
    const float aw = __expf(runM - Mw);
    float Sa = runS * aw;
    Sa += __shfl_xor(Sa, 16, 64);
    Sa += __shfl_xor(Sa, 32, 64);
    #pragma unroll
    for (int j = 0; j < 4; j++) {
        tacc[j].x *= aw; tacc[j].y *= aw; tacc[j].z *= aw; tacc[j].w *= aw;
        tacc[j].x += __shfl_xor(tacc[j].x, 16, 64);
        tacc[j].y += __shfl_xor(tacc[j].y, 16, 64);
        tacc[j].z += __shfl_xor(tacc[j].z, 16, 64);
        tacc[j].w += __shfl_xor(tacc[j].w, 16, 64);
        tacc[j].x += __shfl_xor(tacc[j].x, 32, 64);
        tacc[j].y += __shfl_xor(tacc[j].y, 32, 64);
        tacc[j].z += __shfl_xor(tacc[j].z, 32, 64);
        tacc[j].w += __shfl_xor(tacc[j].w, 32, 64);
    }
    if (lane < 16) {
        #pragma unroll
        for (int j = 0; j < 4; j++)
            ((float4*)shbuf[wave])[q * 2 + 32 * (j >> 1) + (j & 1)] = tacc[j];
    }
    if (lane == 0) { wM[wave] = Mw; wS[wave] = Sa; }
    __syncthreads();
    const float Mb = fmaxf(fmaxf(wM[0], wM[1]), fmaxf(wM[2], wM[3]));
    const float a0 = __expf(wM[0] - Mb), a1 = __expf(wM[1] - Mb),
                a2 = __expf(wM[2] - Mb), a3 = __expf(wM[3] - Mb);
    const float Tc = a0 * shbuf[0][tid] + a1 * shbuf[1][tid] +
                     a2 * shbuf[2][tid] + a3 * shbuf[3][tid];
    Tbuf[((size_t)(b * NCH + chunk)) * D_ + tid] = Tc;
    if (tid == 0)
        stats[b * NCH + chunk] = make_float2(
            Mb, a0 * wS[0] + a1 * wS[1] + a2 * wS[2] + a3 * wS[3]);

    // ---- last block for this b combines all NCH partials ----
    __threadfence();                       // publish Tbuf/stats (device scope)
    if (tid == 0)
        lastFlag = (atomicAdd(&counter[b], 1) == NCH - 1) ? 1 : 0;
    __syncthreads();
    if (!lastFlag) return;
    __threadfence();                       // acquire others' Tbuf/stats

    if (tid < NCH) {
        const float2 st = stats[b * NCH + tid];
        Msh[tid] = st.x; Ssh[tid] = st.y;
    }
    __syncthreads();
    float Mg = -INFINITY;
    #pragma unroll
    for (int c = 0; c < NCH; c++) Mg = fmaxf(Mg, Msh[c]);
    float Sg = 0.f, accg = 0.f;
    #pragma unroll 8
    for (int c = 0; c < NCH; c++) {
        const float a = __expf(Msh[c] - Mg);
        Sg += a * Ssh[c];
        accg += a * Tbuf[((size_t)(b * NCH + c)) * D_ + tid];
    }
    const float zv = accg / Sg;
    if (out) out[b * D_ + tid] = zv;
    if (!flg) {
        vout[b * D_ + tid] = 2.0f * zv;
    } else {
        zsh[tid] = zv;
        __syncthreads();
        float vv = 0.f;
        for (int e = 0; e < D_; e++)
            vv += (P[tid * D_ + e] + P[e * D_ + tid]) * zsh[e];
        vout[b * D_ + tid] = vv;
    }
}

extern "C" void kernel_launch(void* const* d_in, const int* in_sizes, int n_in,
                              void* d_out, int out_size, void* d_ws, size_t ws_size,
                              hipStream_t stream) {
    // inputs: 0=x (unused), 1=z, 2=means, 3=precision, 4=iterations(=10)
    const float* z0    = (const float*)d_in[1];
    const float* means = (const float*)d_in[2];
    const float* P     = (const float*)d_in[3];
    float* out = (float*)d_out;

    char* ws = (char*)d_ws;
    size_t off = 0;
    int*    flag     = (int*)ws;              off = 256;
    int*    counters = (int*)(ws + off);      off += 10 * B_ * sizeof(int);
    off = (off + 255) & ~(size_t)255;
    float*  v        = (float*)(ws + off);    off += (size_t)B_ * D_ * 4;
    float*  Tbuf     = (float*)(ws + off);    off += (size_t)B_ * NCH * D_ * 4;
    float2* stats    = (float2*)(ws + off);   off += (size_t)B_ * NCH * 8;
    off = (off + 255) & ~(size_t)255;
    __half* mh       = (__half*)(ws + off);
    const size_t full_need = off + (size_t)B_ * N_ * D_ * 2;   // + 128 MiB
    const bool use_h = (ws_size >= full_need);

    flag_kernel<<<dim3(1), dim3(256), 0, stream>>>(P, flag, counters, 10 * B_);
    vcalc_kernel<<<dim3(B_), dim3(256), 0, stream>>>(P, z0, flag, v);

    const dim3 grid(NCH, B_), blk(256);
    if (use_h) {
        fused_kernel<1><<<grid, blk, 0, stream>>>(
            means, nullptr, mh, v, P, flag, Tbuf, stats, counters + 0 * B_,
            v, nullptr);
        for (int t = 1; t < 10; t++) {
            fused_kernel<2><<<grid, blk, 0, stream>>>(
                nullptr, mh, nullptr, v, P, flag, Tbuf, stats, counters + t * B_,
                v, (t == 9) ? out : nullptr);
        }
    } else {
        for (int t = 0; t < 10; t++) {
            fused_kernel<0><<<grid, blk, 0, stream>>>(
                means, nullptr, nullptr, v, P, flag, Tbuf, stats, counters + t * B_,
                v, (t == 9) ? out : nullptr);
        }
    }
}